// Round 13
// baseline (50938.382 us; speedup 1.0000x reference)
//
#include <hip/hip_runtime.h>

typedef unsigned short u16;
typedef unsigned int u32;
typedef unsigned long long u64;
typedef float f32x2 __attribute__((ext_vector_type(2)));

#define BATCH 256
#define TT 512
#define HID 256
#define GATES 1024   // 4*HID
#define NEMB 512
#define VOC 27
#define KSF 68       // floats per 64-K slice incl 4-float pad (ks slices 4 banks apart)
#define HROW 272     // 4*KSF floats per batch row

__device__ __forceinline__ float bf1(u16 x){ union{u32 u; float f;} v; v.u = ((u32)x) << 16; return v.f; }
__device__ __forceinline__ u16 f2bf(float f){
  union{float f; u32 u;} v; v.f = f;
  u32 u = v.u;
  return (u16)((u + 0x7fffu + ((u >> 16) & 1u)) >> 16);
}
__device__ __forceinline__ float sigm(float x){ return 1.f / (1.f + __expf(-x)); }
__device__ __forceinline__ f32x2 lo2(float4 v){ f32x2 r; r.x = v.x; r.y = v.y; return r; }
__device__ __forceinline__ f32x2 hi2(float4 v){ f32x2 r; r.x = v.z; r.y = v.w; return r; }

// Sniff storage dtype of b_ih0 (1024 elems, |v| <= 1/16).
__global__ void k_detect(const u16* __restrict__ b, int* __restrict__ flag) {
  int bad = 0;
  for (int k = threadIdx.x; k < 512; k += 64)
    if (((b[2 * k] >> 7) & 0xFF) >= 127) bad = 1;
  unsigned long long m = __ballot(bad);   // single wave
  if (threadIdx.x == 0) flag[0] = (m != 0ULL) ? 0 : 1;
}

__global__ void k_convert(const void* __restrict__ src, float* __restrict__ dst,
                          int n, const int* __restrict__ flag) {
  int i = blockIdx.x * 256 + threadIdx.x;
  if (i >= n) return;
  dst[i] = flag[0] ? bf1(((const u16*)src)[i]) : ((const float*)src)[i];
}

// W0emb[v][g] = sum_i emb[v][i]*w_ih0[g][i] + b_ih0[g] + b_hh0[g]; emb row 26 := 0
__global__ void k_prep(const void* __restrict__ emb, const void* __restrict__ wih,
                       const void* __restrict__ bih, const void* __restrict__ bhh,
                       const int* __restrict__ flag, float* __restrict__ W0) {
  int idx = blockIdx.x * 256 + threadIdx.x;
  if (idx >= VOC * GATES) return;
  int v = idx >> 10, g = idx & (GATES - 1);
  int isbf = flag[0];
  float acc = isbf ? (bf1(((const u16*)bih)[g]) + bf1(((const u16*)bhh)[g]))
                   : (((const float*)bih)[g] + ((const float*)bhh)[g]);
  if (v != 26) {
    float s = 0.f;
    if (isbf) {
      const u16* e = (const u16*)emb + v * NEMB;
      const u16* w = (const u16*)wih + g * NEMB;
      for (int i = 0; i < NEMB; i++) s = fmaf(bf1(e[i]), bf1(w[i]), s);
    } else {
      const float* e = (const float*)emb + v * NEMB;
      const float* w = (const float*)wih + g * NEMB;
      for (int i = 0; i < NEMB; i++) s = fmaf(e[i], w[i], s);
    }
    acc += s;
  }
  W0[idx] = acc;
}

// *** R13: ZERO-SYNC persistent LSTM. 64 blocks x 1024 threads; block owns
// 4 batches END-TO-END (both layers, all 512 steps) — no inter-block
// exchange, flags, or agent-scope ops at all. The 26us/iter cross-block
// round-trip chain (invariant to every within-structure edit R2-R12) is
// simply removed. Cost: each block streams all 3MB of weights per step from
// L2 (8 blocks/XCD share the same 3MB working set -> resident).
// Thread (j = tid>>2 in [0,256), ks = tid&3) owns the 4 gate rows
// {j, 256+j, 512+j, 768+j} over K-slice [64ks, 64ks+64) for ALL 4 batches:
// each weight float4 is read once and feeds 4 batches (16 MACs); each h
// float4 read feeds 4 gates. ks-partials reduced via __shfl_xor(1/2);
// ks==0 lanes run the pointwise inline (c-state in registers) and write h
// back to LDS. h double-buffered by parity -> ONE barrier per timestep
// (phase1 writes h0[pn], phase2 reads it; all other RAW/WAR pairs are
// separated by that barrier + the next iteration's barrier).
// LDS h layout: element k at [(k>>6)*KSF + (k&63)] — ks slices offset by
// 68 floats = 4 banks, so the wave's 4 distinct b128 addresses (16-lane
// broadcast each) hit disjoint bank quads: conflict-free.
__global__ __launch_bounds__(1024) void k_lstm(
    const int* __restrict__ ids, const float* __restrict__ W0,
    const float* __restrict__ whh0, const float* __restrict__ wih1,
    const float* __restrict__ whh1,
    const float* __restrict__ bih1, const float* __restrict__ bhh1,
    float* __restrict__ h1out)
{
  const int tid = threadIdx.x;
  const int bid = blockIdx.x;         // [0,64): batches [4bid, 4bid+4)
  const int ks  = tid & 3;            // K-slice
  const int j   = tid >> 2;           // [0,256)
  const bool owner = (ks == 0);

  __shared__ __align__(16) float h0buf[2][4][HROW];
  __shared__ __align__(16) float h1buf[2][4][HROW];
  __shared__ int ids_l[4][TT];

  // zero parity-0 buffers (read at t=0)
  {
    float* z0 = &h0buf[0][0][0];
    float* z1 = &h1buf[0][0][0];
    for (int i = tid; i < 4 * HROW; i += 1024) { z0[i] = 0.f; z1[i] = 0.f; }
  }
  #pragma unroll
  for (int u = 0; u < 2; ++u) {
    int e = tid + 1024 * u;           // [0,2048)
    int b = e >> 9, tt = e & 511;
    ids_l[b][tt] = ids[(bid * 4 + b) * TT + tt];
  }
  __syncthreads();

  const size_t ko = (size_t)ks * 64;
  const float4* wl0_[4]; const float4* wi_[4]; const float4* wh_[4];
  #pragma unroll
  for (int g = 0; g < 4; ++g) {
    size_t r = (size_t)(g * 256 + j) * HID + ko;
    wl0_[g] = (const float4*)(whh0 + r);
    wi_[g]  = (const float4*)(wih1 + r);
    wh_[g]  = (const float4*)(whh1 + r);
  }
  float bs[4];
  #pragma unroll
  for (int g = 0; g < 4; ++g) bs[g] = bih1[g * 256 + j] + bhh1[g * 256 + j];

  const int jm = ((j >> 6) * KSF) + (j & 63);   // LDS slot for element j
  float c0r[4] = {0.f, 0.f, 0.f, 0.f};
  float c1r[4] = {0.f, 0.f, 0.f, 0.f};

  for (int t = 0; t < TT; ++t) {
    const int pc = t & 1, pn = pc ^ 1;

    // prefetch x-gate terms (owner lanes; L2 hits; hides under phase-1 gemm)
    float xg[4][4];
    if (owner) {
      #pragma unroll
      for (int b = 0; b < 4; ++b) {
        const float* xr = W0 + (size_t)ids_l[b][t] * GATES + j;
        xg[0][b] = xr[0];   xg[1][b] = xr[256];
        xg[2][b] = xr[512]; xg[3][b] = xr[768];
      }
    }

    // ---------- PHASE 1: layer0 step t (reads h0buf[pc], writes h0buf[pn]) ----------
    {
      const float4* hb[4];
      #pragma unroll
      for (int b = 0; b < 4; ++b) hb[b] = (const float4*)&h0buf[pc][b][ks * KSF];
      f32x2 a[4][4];
      #pragma unroll
      for (int g = 0; g < 4; ++g)
        #pragma unroll
        for (int b = 0; b < 4; ++b) { a[g][b].x = 0.f; a[g][b].y = 0.f; }
      #pragma unroll 4
      for (int k = 0; k < 16; ++k) {
        float4 w0 = wl0_[0][k], w1 = wl0_[1][k], w2 = wl0_[2][k], w3 = wl0_[3][k];
        float4 x0 = hb[0][k], x1 = hb[1][k], x2 = hb[2][k], x3 = hb[3][k];
        a[0][0] = lo2(w0)*lo2(x0) + a[0][0]; a[0][0] = hi2(w0)*hi2(x0) + a[0][0];
        a[0][1] = lo2(w0)*lo2(x1) + a[0][1]; a[0][1] = hi2(w0)*hi2(x1) + a[0][1];
        a[0][2] = lo2(w0)*lo2(x2) + a[0][2]; a[0][2] = hi2(w0)*hi2(x2) + a[0][2];
        a[0][3] = lo2(w0)*lo2(x3) + a[0][3]; a[0][3] = hi2(w0)*hi2(x3) + a[0][3];
        a[1][0] = lo2(w1)*lo2(x0) + a[1][0]; a[1][0] = hi2(w1)*hi2(x0) + a[1][0];
        a[1][1] = lo2(w1)*lo2(x1) + a[1][1]; a[1][1] = hi2(w1)*hi2(x1) + a[1][1];
        a[1][2] = lo2(w1)*lo2(x2) + a[1][2]; a[1][2] = hi2(w1)*hi2(x2) + a[1][2];
        a[1][3] = lo2(w1)*lo2(x3) + a[1][3]; a[1][3] = hi2(w1)*hi2(x3) + a[1][3];
        a[2][0] = lo2(w2)*lo2(x0) + a[2][0]; a[2][0] = hi2(w2)*hi2(x0) + a[2][0];
        a[2][1] = lo2(w2)*lo2(x1) + a[2][1]; a[2][1] = hi2(w2)*hi2(x1) + a[2][1];
        a[2][2] = lo2(w2)*lo2(x2) + a[2][2]; a[2][2] = hi2(w2)*hi2(x2) + a[2][2];
        a[2][3] = lo2(w2)*lo2(x3) + a[2][3]; a[2][3] = hi2(w2)*hi2(x3) + a[2][3];
        a[3][0] = lo2(w3)*lo2(x0) + a[3][0]; a[3][0] = hi2(w3)*hi2(x0) + a[3][0];
        a[3][1] = lo2(w3)*lo2(x1) + a[3][1]; a[3][1] = hi2(w3)*hi2(x1) + a[3][1];
        a[3][2] = lo2(w3)*lo2(x2) + a[3][2]; a[3][2] = hi2(w3)*hi2(x2) + a[3][2];
        a[3][3] = lo2(w3)*lo2(x3) + a[3][3]; a[3][3] = hi2(w3)*hi2(x3) + a[3][3];
      }
      float s[4][4];
      #pragma unroll
      for (int g = 0; g < 4; ++g)
        #pragma unroll
        for (int b = 0; b < 4; ++b) {
          float v = a[g][b].x + a[g][b].y;
          v += __shfl_xor(v, 1);
          v += __shfl_xor(v, 2);
          s[g][b] = v;
        }
      if (owner) {
        #pragma unroll
        for (int b = 0; b < 4; ++b) {
          float gi = sigm(s[0][b] + xg[0][b]);
          float gf = sigm(s[1][b] + xg[1][b]);
          float gg = tanhf(s[2][b] + xg[2][b]);
          float go = sigm(s[3][b] + xg[3][b]);
          c0r[b] = fmaf(gf, c0r[b], gi * gg);
          h0buf[pn][b][jm] = go * tanhf(c0r[b]);
        }
      }
    }
    __syncthreads();   // h0[t] visible; the ONLY barrier per timestep

    // ---------- PHASE 2: layer1 step t (x = h0buf[pn], h = h1buf[pc]) ----------
    {
      const float4* xb[4]; const float4* hb[4];
      #pragma unroll
      for (int b = 0; b < 4; ++b) {
        xb[b] = (const float4*)&h0buf[pn][b][ks * KSF];
        hb[b] = (const float4*)&h1buf[pc][b][ks * KSF];
      }
      f32x2 a[4][4];
      #pragma unroll
      for (int g = 0; g < 4; ++g)
        #pragma unroll
        for (int b = 0; b < 4; ++b) { a[g][b].x = 0.f; a[g][b].y = 0.f; }
      #pragma unroll 2
      for (int k = 0; k < 16; ++k) {
        float4 x0 = xb[0][k], x1 = xb[1][k], x2 = xb[2][k], x3 = xb[3][k];
        {
          float4 w0 = wi_[0][k], w1 = wi_[1][k], w2 = wi_[2][k], w3 = wi_[3][k];
          a[0][0] = lo2(w0)*lo2(x0) + a[0][0]; a[0][0] = hi2(w0)*hi2(x0) + a[0][0];
          a[0][1] = lo2(w0)*lo2(x1) + a[0][1]; a[0][1] = hi2(w0)*hi2(x1) + a[0][1];
          a[0][2] = lo2(w0)*lo2(x2) + a[0][2]; a[0][2] = hi2(w0)*hi2(x2) + a[0][2];
          a[0][3] = lo2(w0)*lo2(x3) + a[0][3]; a[0][3] = hi2(w0)*hi2(x3) + a[0][3];
          a[1][0] = lo2(w1)*lo2(x0) + a[1][0]; a[1][0] = hi2(w1)*hi2(x0) + a[1][0];
          a[1][1] = lo2(w1)*lo2(x1) + a[1][1]; a[1][1] = hi2(w1)*hi2(x1) + a[1][1];
          a[1][2] = lo2(w1)*lo2(x2) + a[1][2]; a[1][2] = hi2(w1)*hi2(x2) + a[1][2];
          a[1][3] = lo2(w1)*lo2(x3) + a[1][3]; a[1][3] = hi2(w1)*hi2(x3) + a[1][3];
          a[2][0] = lo2(w2)*lo2(x0) + a[2][0]; a[2][0] = hi2(w2)*hi2(x0) + a[2][0];
          a[2][1] = lo2(w2)*lo2(x1) + a[2][1]; a[2][1] = hi2(w2)*hi2(x1) + a[2][1];
          a[2][2] = lo2(w2)*lo2(x2) + a[2][2]; a[2][2] = hi2(w2)*hi2(x2) + a[2][2];
          a[2][3] = lo2(w2)*lo2(x3) + a[2][3]; a[2][3] = hi2(w2)*hi2(x3) + a[2][3];
          a[3][0] = lo2(w3)*lo2(x0) + a[3][0]; a[3][0] = hi2(w3)*hi2(x0) + a[3][0];
          a[3][1] = lo2(w3)*lo2(x1) + a[3][1]; a[3][1] = hi2(w3)*hi2(x1) + a[3][1];
          a[3][2] = lo2(w3)*lo2(x2) + a[3][2]; a[3][2] = hi2(w3)*hi2(x2) + a[3][2];
          a[3][3] = lo2(w3)*lo2(x3) + a[3][3]; a[3][3] = hi2(w3)*hi2(x3) + a[3][3];
        }
        float4 h0v = hb[0][k], h1v = hb[1][k], h2v = hb[2][k], h3v = hb[3][k];
        {
          float4 w0 = wh_[0][k], w1 = wh_[1][k], w2 = wh_[2][k], w3 = wh_[3][k];
          a[0][0] = lo2(w0)*lo2(h0v) + a[0][0]; a[0][0] = hi2(w0)*hi2(h0v) + a[0][0];
          a[0][1] = lo2(w0)*lo2(h1v) + a[0][1]; a[0][1] = hi2(w0)*hi2(h1v) + a[0][1];
          a[0][2] = lo2(w0)*lo2(h2v) + a[0][2]; a[0][2] = hi2(w0)*hi2(h2v) + a[0][2];
          a[0][3] = lo2(w0)*lo2(h3v) + a[0][3]; a[0][3] = hi2(w0)*hi2(h3v) + a[0][3];
          a[1][0] = lo2(w1)*lo2(h0v) + a[1][0]; a[1][0] = hi2(w1)*hi2(h0v) + a[1][0];
          a[1][1] = lo2(w1)*lo2(h1v) + a[1][1]; a[1][1] = hi2(w1)*hi2(h1v) + a[1][1];
          a[1][2] = lo2(w1)*lo2(h2v) + a[1][2]; a[1][2] = hi2(w1)*hi2(h2v) + a[1][2];
          a[1][3] = lo2(w1)*lo2(h3v) + a[1][3]; a[1][3] = hi2(w1)*hi2(h3v) + a[1][3];
          a[2][0] = lo2(w2)*lo2(h0v) + a[2][0]; a[2][0] = hi2(w2)*hi2(h0v) + a[2][0];
          a[2][1] = lo2(w2)*lo2(h1v) + a[2][1]; a[2][1] = hi2(w2)*hi2(h1v) + a[2][1];
          a[2][2] = lo2(w2)*lo2(h2v) + a[2][2]; a[2][2] = hi2(w2)*hi2(h2v) + a[2][2];
          a[2][3] = lo2(w2)*lo2(h3v) + a[2][3]; a[2][3] = hi2(w2)*hi2(h3v) + a[2][3];
          a[3][0] = lo2(w3)*lo2(h0v) + a[3][0]; a[3][0] = hi2(w3)*hi2(h0v) + a[3][0];
          a[3][1] = lo2(w3)*lo2(h1v) + a[3][1]; a[3][1] = hi2(w3)*hi2(h1v) + a[3][1];
          a[3][2] = lo2(w3)*lo2(h2v) + a[3][2]; a[3][2] = hi2(w3)*hi2(h2v) + a[3][2];
          a[3][3] = lo2(w3)*lo2(h3v) + a[3][3]; a[3][3] = hi2(w3)*hi2(h3v) + a[3][3];
        }
      }
      float s[4][4];
      #pragma unroll
      for (int g = 0; g < 4; ++g)
        #pragma unroll
        for (int b = 0; b < 4; ++b) {
          float v = a[g][b].x + a[g][b].y;
          v += __shfl_xor(v, 1);
          v += __shfl_xor(v, 2);
          s[g][b] = v;
        }
      if (owner) {
        #pragma unroll
        for (int b = 0; b < 4; ++b) {
          float gi = sigm(s[0][b] + bs[0]);
          float gf = sigm(s[1][b] + bs[1]);
          float gg = tanhf(s[2][b] + bs[2]);
          float go = sigm(s[3][b] + bs[3]);
          c1r[b] = fmaf(gf, c1r[b], gi * gg);
          float hv = go * tanhf(c1r[b]);
          h1buf[pn][b][jm] = hv;
          if (t == TT - 1) h1out[(bid * 4 + b) * HID + j] = hv;
        }
      }
    }
    // no second barrier needed: next iteration's phase-1 barrier separates
    // this phase-2's h1buf[pn] writes from the next phase-2's reads, and
    // phase-1(t+1) touches only h0buf (write target = other parity).
  }
}

// MLP head: out[b] = fc2_w . relu(fc1_w @ h[b] + fc1_b) + fc2_b
__global__ __launch_bounds__(128) void k_fc(
    const float* __restrict__ hfin,
    const void* __restrict__ fc1w, const void* __restrict__ fc1b,
    const void* __restrict__ fc2w, const void* __restrict__ fc2b,
    const int* __restrict__ flag, void* __restrict__ out) {
  int b = blockIdx.x, j = threadIdx.x;  // 128 threads
  __shared__ float red[128];
  const float* h = hfin + b * HID;
  int isbf = flag[0];
  float acc = isbf ? bf1(((const u16*)fc1b)[j]) : ((const float*)fc1b)[j];
  if (isbf) {
    const u16* w = (const u16*)fc1w + j * HID;
    for (int k = 0; k < HID; k++) acc = fmaf(bf1(w[k]), h[k], acc);
  } else {
    const float* w = (const float*)fc1w + j * HID;
    for (int k = 0; k < HID; k++) acc = fmaf(w[k], h[k], acc);
  }
  acc = fmaxf(acc, 0.f);
  float w2 = isbf ? bf1(((const u16*)fc2w)[j]) : ((const float*)fc2w)[j];
  red[j] = acc * w2;
  __syncthreads();
  for (int s = 64; s > 0; s >>= 1) {
    if (j < s) red[j] += red[j + s];
    __syncthreads();
  }
  if (j == 0) {
    float b2 = isbf ? bf1(((const u16*)fc2b)[0]) : ((const float*)fc2b)[0];
    float r = red[0] + b2;
    if (isbf) ((u16*)out)[b] = f2bf(r);
    else      ((float*)out)[b] = r;
  }
}

extern "C" void kernel_launch(void* const* d_in, const int* in_sizes, int n_in,
                              void* d_out, int out_size, void* d_ws, size_t ws_size,
                              hipStream_t stream) {
  const int* ids   = (const int*)d_in[0];
  const void* emb  = d_in[1];
  const void* wih0 = d_in[2];
  const void* whh0 = d_in[3];
  const void* bih0 = d_in[4];
  const void* bhh0 = d_in[5];
  const void* wih1 = d_in[6];
  const void* whh1 = d_in[7];
  const void* bih1 = d_in[8];
  const void* bhh1 = d_in[9];
  const void* fc1w = d_in[10];
  const void* fc1b = d_in[11];
  const void* fc2w = d_in[12];
  const void* fc2b = d_in[13];

  float* ws = (float*)d_ws;
  int*   flag    = (int*)ws;                  // 16-float pad
  float* W0emb   = ws + 16;                   // 27648
  float* whh0_f  = W0emb  + VOC * GATES;      // 262144
  float* wih1_f  = whh0_f + GATES * HID;      // 262144
  float* whh1_f  = wih1_f + GATES * HID;      // 262144
  float* bih1_f  = whh1_f + GATES * HID;      // 1024
  float* bhh1_f  = bih1_f + GATES;            // 1024
  float* h1B     = bhh1_f + GATES;            // 65536 (final hidden out)

  k_detect<<<1, 64, 0, stream>>>((const u16*)bih0, flag);

  k_convert<<<(GATES * HID + 255) / 256, 256, 0, stream>>>(whh0, whh0_f, GATES * HID, flag);
  k_convert<<<(GATES * HID + 255) / 256, 256, 0, stream>>>(wih1, wih1_f, GATES * HID, flag);
  k_convert<<<(GATES * HID + 255) / 256, 256, 0, stream>>>(whh1, whh1_f, GATES * HID, flag);
  k_convert<<<(GATES + 255) / 256, 256, 0, stream>>>(bih1, bih1_f, GATES, flag);
  k_convert<<<(GATES + 255) / 256, 256, 0, stream>>>(bhh1, bhh1_f, GATES, flag);

  k_prep<<<(VOC * GATES + 255) / 256, 256, 0, stream>>>(emb, wih0, bih0, bhh0, flag, W0emb);

  k_lstm<<<64, 1024, 0, stream>>>(ids, W0emb, whh0_f, wih1_f, whh1_f,
                                  bih1_f, bhh1_f, h1B);

  k_fc<<<BATCH, 128, 0, stream>>>(h1B, fc1w, fc1b, fc2w, fc2b, flag, d_out);
}